// Round 11
// baseline (1156.005 us; speedup 1.0000x reference)
//
#include <hip/hip_runtime.h>
#include <stdint.h>

// Persistent-kernel RNN: 256 wgs (1/CU), batch split 16 ways, h exchanged via
// MALL (sc0 sc1) + per-group flags (R2 protocol).
// R13 = R12 (register-resident W, direct-global A bursts, tied vmcnt waits,
// zero-bank-conflict scratch — PASSED at 1153us) + ONE change: PER-WAVE GATE.
//  R12's null result (no LDS, no conflicts, 4 barriers -> same ~4.5us/step)
//  proves the floor is the serialized exchange chain + max-of-16 straggler.
//  k-split-by-wave means wave wv consumes ONLY producers jg' in [4wv,4wv+4).
//  Gate: lanes 0-3 of each wave poll those 4 flags (wave lockstep: a divergent
//  spin on lanes 0-3 gates all 64 lanes — one PC per wave); NO __syncthreads
//  before the loads. Each wave's A-burst + 64 MFMAs (~1.5us chain) overlaps the
//  remaining producers' completion instead of waiting for the global max.
//  Correctness join unchanged: the reduction barrier_lgkm collects all 4 waves
//  (collectively all 16 flags observed) BEFORE any hout store -> the R2 WAW
//  induction holds verbatim. s_sleep 1 backoff added to all spins.
// Lessons kept: tied "+v" vmcnt waits + sched_barrier(0) (R11 crash, R12 fix);
// sc0-only spin hangs (R3); buffer_inv sc1 = L2 nuke (R4); data-polling retry
// storms (R5/R9); scope bits don't change exchange cost (R5==R6).

#define BATCH 512
#define SEQ   256
#define HID   1024
#define CLS   128

#define GB 16          // batch groups
#define GJ 16          // hidden slices
#define BT 32          // batch rows per wg
#define JT 64          // hidden cols per wg
#define KC 256         // head staging chunk (halves)
#define SSTR 260       // head stage row stride (halves)
#define HSTR 68        // h exchange row stride (halves)
#define HS_OFF 16384   // halves: hS overlay at byte 32768 (above 32KB scratch)
#define SMEM_BYTES (32768 + BT * HSTR * 2)   // 37120 B
#define HBUF_HALVES (BATCH * HID)            // 1 MB per buffer

typedef __attribute__((ext_vector_type(8))) short  bf16x8;
typedef __attribute__((ext_vector_type(4))) short  s16x4;
typedef __attribute__((ext_vector_type(4))) float  f32x4;
typedef __attribute__((ext_vector_type(4))) int    i32x4;
typedef __attribute__((ext_vector_type(2))) unsigned int u32x2;

__device__ __forceinline__ unsigned short f2bf(float f) {
  unsigned int u = __float_as_uint(f);
  u = (u + 0x7FFFu + ((u >> 16) & 1u)) >> 16;   // RNE
  return (unsigned short)u;
}
__device__ __forceinline__ float b2f(short h) {
  return __uint_as_float(((unsigned int)(unsigned short)h) << 16);
}

// ---- device-coherent (MALL) protocol accesses ----
__device__ __forceinline__ void store_flag(int* p, int v) {
  asm volatile("global_store_dword %0, %1, off sc0 sc1" :: "v"(p), "v"(v) : "memory");
}
__device__ __forceinline__ int load_flag(const int* p) {
  int v;
  asm volatile("global_load_dword %0, %1, off sc0 sc1\n\t"
               "s_waitcnt vmcnt(0)" : "=v"(v) : "v"(p) : "memory");
  return v;
}
__device__ __forceinline__ void store16(void* p, i32x4 v) {
  asm volatile("global_store_dwordx4 %0, %1, off sc0 sc1" :: "v"(p), "v"(v) : "memory");
}
__device__ __forceinline__ void waitcnt0() {
  asm volatile("s_waitcnt vmcnt(0)" ::: "memory");
}
// raw workgroup barrier: drains LDS ops only
__device__ __forceinline__ void barrier_lgkm() {
  asm volatile("s_waitcnt lgkmcnt(0)\n\ts_barrier" ::: "memory");
}
// head staging: 4x dwordx4, 128B apart (512B chunk)
__device__ __forceinline__ void issue4(const void* p, i32x4& a, i32x4& b, i32x4& c, i32x4& d) {
  asm volatile(
    "global_load_dwordx4 %0, %4, off sc0 sc1\n\t"
    "global_load_dwordx4 %1, %4, off offset:128 sc0 sc1\n\t"
    "global_load_dwordx4 %2, %4, off offset:256 sc0 sc1\n\t"
    "global_load_dwordx4 %3, %4, off offset:384 sc0 sc1"
    : "=&v"(a), "=&v"(b), "=&v"(c), "=&v"(d)
    : "v"(p) : "memory");
}
// A-fragment burst: 4x dwordx4, 64B apart (4 consecutive k-steps of one row)
__device__ __forceinline__ void issue4_64(const void* p, i32x4& a, i32x4& b, i32x4& c, i32x4& d) {
  asm volatile(
    "global_load_dwordx4 %0, %4, off sc0 sc1\n\t"
    "global_load_dwordx4 %1, %4, off offset:64 sc0 sc1\n\t"
    "global_load_dwordx4 %2, %4, off offset:128 sc0 sc1\n\t"
    "global_load_dwordx4 %3, %4, off offset:192 sc0 sc1"
    : "=&v"(a), "=&v"(b), "=&v"(c), "=&v"(d)
    : "v"(p) : "memory");
}

__device__ __forceinline__ void wr16(short* p, i32x4 v) {  // 16 B to LDS as 2x b64
  u32x2 lo, hi;
  lo.x = (unsigned)v.x; lo.y = (unsigned)v.y;
  hi.x = (unsigned)v.z; hi.y = (unsigned)v.w;
  *(u32x2*)p = lo;
  *(u32x2*)(p + 4) = hi;
}
__device__ __forceinline__ float tanh_fast(float z) {
  float e = __expf(2.f * z);
  return 1.f - 2.f / (e + 1.f);
}

#define MFMA(a, b, c) __builtin_amdgcn_mfma_f32_16x16x32_bf16((a), (b), (c), 0, 0, 0)

__global__ void __launch_bounds__(256, 1)
rnn_persistent(const float* __restrict__ x, const float* __restrict__ Whx,
               const float* __restrict__ Whh, const float* __restrict__ bh,
               const float* __restrict__ Wph, const float* __restrict__ bp,
               float* __restrict__ out, unsigned short* hbuf, int* flags)
{
  extern __shared__ short smem[];
  float* scr = (float*)smem;            // 32KB reduction scratch (head reuses)
  short* hS  = smem + HS_OFF;           // [BT][HSTR] exchange overlay

  const int tid  = threadIdx.x;
  const int bg   = blockIdx.x & 15;
  const int jg   = blockIdx.x >> 4;
  const int lane = tid & 63;
  const int wv   = tid >> 6;          // wave = output col-tile AND k-quarter
  const int l15  = lane & 15;
  const int quad = lane >> 4;

  // ---- W_hh into REGISTERS: cols jg*64+ct*16+l15, k = wv*256+ks*32+quad*8 ----
  bf16x8 barr[4][8];
#pragma unroll
  for (int ct = 0; ct < 4; ++ct) {
#pragma unroll
    for (int ks = 0; ks < 8; ++ks) {
      const float* wp = Whh + (jg * JT + ct * 16 + l15) * HID
                            + wv * 256 + ks * 32 + quad * 8;
      float4 fA = *(const float4*)(wp);
      float4 fB = *(const float4*)(wp + 4);
      union { bf16x8 v8; s16x4 h[2]; } u;
      u.h[0].x = (short)f2bf(fA.x); u.h[0].y = (short)f2bf(fA.y);
      u.h[0].z = (short)f2bf(fA.z); u.h[0].w = (short)f2bf(fA.w);
      u.h[1].x = (short)f2bf(fB.x); u.h[1].y = (short)f2bf(fB.y);
      u.h[1].z = (short)f2bf(fB.z); u.h[1].w = (short)f2bf(fB.w);
      barr[ct][ks] = u.v8;
    }
  }

  const int j = jg * JT + wv * 16 + l15;       // this lane's output column
  const float whx = Whx[j];
  const float bhv = bh[j];
  const int grow0 = bg * BT + quad * 4;        // batch row base (row-tile 0)

  // exchange thread mapping: 64 B per thread
  const int sr  = tid >> 3;               // 0..31 row
  const int seg = tid & 7;                // 0..7

  int* myflags = flags + bg * 64;         // 16 flags, one 64B line per bg

  for (int t = 0; t < SEQ; ++t) {
    const unsigned short* hin = hbuf + ((t + 1) & 1) * HBUF_HALVES;
    unsigned short*      hout = hbuf + (t & 1) * HBUF_HALVES;

    f32x4 acc00 = {0,0,0,0}, acc01 = {0,0,0,0}, acc02 = {0,0,0,0}, acc03 = {0,0,0,0};
    f32x4 acc10 = {0,0,0,0}, acc11 = {0,0,0,0}, acc12 = {0,0,0,0}, acc13 = {0,0,0,0};

    // x for this step (plain loads; drained by the spin's vmcnt0 / tied wait)
    float xv0[4], xv1[4];
    {
      const float* xp = x + grow0 * SEQ + t;
#pragma unroll
      for (int rg = 0; rg < 4; ++rg) {
        xv0[rg] = xp[rg * SEQ];
        xv1[rg] = xp[(16 + rg) * SEQ];
      }
    }

    if (t > 0) {
      // PER-WAVE gate: wave wv's A (k-quarter wv) comes from producers
      // jg' in [4wv, 4wv+4). Wave lockstep: lanes 4-63 are exec-masked while
      // lanes 0-3 spin, so the whole wave is gated (single PC). The cross-wave
      // join for the WAW guarantee is the reduction barrier below, reached
      // only after all 4 waves (collectively all 16 flags) passed their gates.
      if (lane < 4) {
        while (load_flag(myflags + wv * 4 + lane) < t) {
          asm volatile("s_sleep 1" ::: "memory");
        }
      }

      // A fragments direct from global in MFMA layout:
      // row l15 (+16), k-halves = wv*256 + quad*8 + ks*32. 16-deep burst.
      const short* pA0 = (const short*)hin + (bg * BT + l15) * HID
                         + wv * 256 + quad * 8;
      const short* pA1 = pA0 + 16 * HID;
      i32x4 A0, A1, A2, A3, A4, A5, A6, A7, A8, A9, A10, A11, A12, A13, A14, A15;
      issue4_64(pA0,        A0,  A1,  A2,  A3);    // rt0 ks0..3
      issue4_64(pA0 + 128,  A4,  A5,  A6,  A7);    // rt0 ks4..7
      issue4_64(pA1,        A8,  A9,  A10, A11);   // rt1 ks0..3
      issue4_64(pA1 + 128,  A12, A13, A14, A15);   // rt1 ks4..7

      // TIED wait (rule #18): bind every A reg so the MFMAs below cannot be
      // scheduled above the s_waitcnt; sched_barrier pins the boundary.
      asm volatile("s_waitcnt vmcnt(0)"
                   : "+v"(A0), "+v"(A1), "+v"(A2),  "+v"(A3),
                     "+v"(A4), "+v"(A5), "+v"(A6),  "+v"(A7),
                     "+v"(A8), "+v"(A9), "+v"(A10), "+v"(A11),
                     "+v"(A12), "+v"(A13), "+v"(A14), "+v"(A15)
                   :: "memory");
      __builtin_amdgcn_sched_barrier(0);

#define KSTEP(Ar0, Ar1, KS) { \
      bf16x8 _a0 = *(const bf16x8*)&(Ar0); \
      bf16x8 _a1 = *(const bf16x8*)&(Ar1); \
      acc00 = MFMA(_a0, barr[0][KS], acc00); acc10 = MFMA(_a1, barr[0][KS], acc10); \
      acc01 = MFMA(_a0, barr[1][KS], acc01); acc11 = MFMA(_a1, barr[1][KS], acc11); \
      acc02 = MFMA(_a0, barr[2][KS], acc02); acc12 = MFMA(_a1, barr[2][KS], acc12); \
      acc03 = MFMA(_a0, barr[3][KS], acc03); acc13 = MFMA(_a1, barr[3][KS], acc13); }
      KSTEP(A0, A8,  0) KSTEP(A1, A9,  1) KSTEP(A2, A10, 2) KSTEP(A3, A11, 3)
      KSTEP(A4, A12, 4) KSTEP(A5, A13, 5) KSTEP(A6, A14, 6) KSTEP(A7, A15, 7)
#undef KSTEP
    }

    // ---- cross-wave k-reduction: scr slot (group, lane), 16B lane-contiguous ----
    barrier_lgkm();   // JOIN: all 4 waves passed gates; prior-step readers done
#pragma unroll
    for (int ct = 0; ct < 4; ++ct) {
      f32x4 w0 = (ct == 0) ? acc00 : (ct == 1) ? acc01 : (ct == 2) ? acc02 : acc03;
      f32x4 w1 = (ct == 0) ? acc10 : (ct == 1) ? acc11 : (ct == 2) ? acc12 : acc13;
      *(f32x4*)(scr + (((ct * 2 + 0) * 4 + wv) * 64 + lane) * 4) = w0;
      *(f32x4*)(scr + (((ct * 2 + 1) * 4 + wv) * 64 + lane) * 4) = w1;
    }
    barrier_lgkm();
    {
      f32x4 f0 = {0,0,0,0}, f1 = {0,0,0,0};
#pragma unroll
      for (int w = 0; w < 4; ++w) {
        f0 += *(const f32x4*)(scr + (((wv * 2 + 0) * 4 + w) * 64 + lane) * 4);
        f1 += *(const f32x4*)(scr + (((wv * 2 + 1) * 4 + w) * 64 + lane) * 4);
      }
      // h = tanh(acc + x*whx + bh) -> hS (wave wv owns col-tile wv)
#pragma unroll
      for (int rg = 0; rg < 4; ++rg) {
        float z0 = f0[rg] + xv0[rg] * whx + bhv;
        hS[(quad * 4 + rg) * HSTR + wv * 16 + l15] = (short)f2bf(tanh_fast(z0));
        float z1 = f1[rg] + xv1[rg] * whx + bhv;
        hS[(16 + quad * 4 + rg) * HSTR + wv * 16 + l15] = (short)f2bf(tanh_fast(z1));
      }
    }
    barrier_lgkm();   // hS complete
    {
      const short* hsrc = hS + sr * HSTR + seg * 8;
      u32x2 lo = *(const u32x2*)(hsrc);
      u32x2 hi = *(const u32x2*)(hsrc + 4);
      i32x4 sv; sv.x = (int)lo.x; sv.y = (int)lo.y; sv.z = (int)hi.x; sv.w = (int)hi.y;
      unsigned short* dst = hout + (bg * BT + sr) * HID + jg * JT + seg * 8;
      store16(dst, sv);
    }
    waitcnt0();          // this thread's 4KB-coalesced store retired at MALL
    barrier_lgkm();      // all threads retired before the flag release
    if (tid == 0) store_flag(myflags + jg, t + 1);
  }

  // ---- output head: out[b, jg*8+cc] = h_last . W_ph[c] + b_p ----
  if (tid < GJ) {
    while (load_flag(myflags + tid) < SEQ) {
      asm volatile("s_sleep 1" ::: "memory");
    }
  }
  __syncthreads();

  const unsigned short* hlast = hbuf + ((SEQ - 1) & 1) * HBUF_HALVES;
  short* sS = smem;                       // head staging overlays scratch
  const int cc = tid & 7;
  const int cg = jg * 8 + cc;
  const int hr = tid >> 3;
  float acc = 0.f;
  const char* lbase = (const char*)(hlast + (bg * BT + sr) * HID) + seg * 16;
  short* sdst = sS + sr * SSTR + seg * 8;
  for (int c = 0; c < 4; ++c) {
    __syncthreads();
    i32x4 p0, p1, p2, p3;
    issue4(lbase + c * 512, p0, p1, p2, p3);
    waitcnt0();
    wr16(sdst, p0); wr16(sdst + 64, p1); wr16(sdst + 128, p2); wr16(sdst + 192, p3);
    __syncthreads();
    const float* wp = Wph + cg * HID + c * KC;
    const short* hs = sS + hr * SSTR;
#pragma unroll 8
    for (int k4 = 0; k4 < 64; ++k4) {
      float4 w  = *(const float4*)(wp + k4 * 4);
      s16x4 hv  = *(const s16x4*)(hs + k4 * 4);
      acc += b2f(hv.x) * w.x + b2f(hv.y) * w.y + b2f(hv.z) * w.z + b2f(hv.w) * w.w;
    }
  }
  out[(bg * BT + hr) * CLS + cg] = acc + bp[cg];
}

extern "C" void kernel_launch(void* const* d_in, const int* in_sizes, int n_in,
                              void* d_out, int out_size, void* d_ws, size_t ws_size,
                              hipStream_t stream) {
  const float* x   = (const float*)d_in[0];
  const float* Whx = (const float*)d_in[1];
  const float* Whh = (const float*)d_in[2];
  const float* bh  = (const float*)d_in[3];
  const float* Wph = (const float*)d_in[4];
  const float* bp  = (const float*)d_in[5];
  float* out = (float*)d_out;

  unsigned short* hbuf = (unsigned short*)d_ws;
  int* flags = (int*)((char*)d_ws + (size_t)2 * HBUF_HALVES * 2);

  // Zero flags each launch (stream-ordered, capture-safe): closes the
  // cross-launch race where stale flags (=SEQ) would let consumers run ahead.
  hipMemsetAsync(flags, 0, GB * 64 * sizeof(int), stream);

  hipFuncSetAttribute(reinterpret_cast<const void*>(rnn_persistent),
                      hipFuncAttributeMaxDynamicSharedMemorySize, SMEM_BYTES);

  rnn_persistent<<<dim3(GB * GJ), dim3(256), SMEM_BYTES, stream>>>(
      x, Whx, Whh, bh, Wph, bp, out, hbuf, flags);
}

// Round 13
// 968.109 us; speedup vs baseline: 1.1941x; 1.1941x over previous
//
#include <hip/hip_runtime.h>
#include <stdint.h>

// Persistent-kernel RNN: 256 wgs (1/CU), h exchanged via MALL (sc0 sc1) +
// per-group flags (R2 protocol).
// R15 = R14 (GB=32 x GJ=8 decomposition) + head-staging ADDRESS FIX.
//  R14 failed absmax=1.25: the output head staged each thread's contiguous
//  128B (seg*128) with 64-byte-stride loads at bases +0/+64 — overlapping
//  {0,64,128,192}+{64,128,192,256} instead of {0..112} — then wrote them to
//  contiguous LDS slots: h_last scrambled, head output wrong. Recurrence path
//  (R12-verified) was untouched. Fix: issue4_16 (16B strides) at +0 and +64.
// R14 thesis (unchanged, now actually tested): all 8 prior variants moved
//  16 MB/step of h reads through the MALL and all landed at ~4 TB/s read rate
//  => MALL coherent-read BW is the floor. GJ=8 halves the read amplification:
//  per wg 16 rows x 2KB = 32 KB/step -> 8 MB/step chip-wide.
//  W_hh per wg = 256 KB -> REGISTERS (R12 scheme): barr[8][8] bf16x8 = 256
//  VGPR/wave (wave wv = k-quarter). A direct from global in MFMA fragment
//  layout, 8-deep burst, register-TIED vmcnt wait + sched_barrier (R11 crash
//  lesson). k-reduction via lane-contiguous f32x4 scratch (0 conflicts, R12).
// Lessons kept: tied "+v" waits (R11/R12); sc0-only spin hangs (R3);
// buffer_inv sc1 = L2 nuke (R4); data-polling retry storms (R5/R9); scope
// bits don't change exchange cost (R5==R6).

#define BATCH 512
#define SEQ   256
#define HID   1024
#define CLS   128

#define GB 32          // batch groups
#define GJ 8           // hidden slices (consumers per h byte — the lever)
#define BT 16          // batch rows per wg
#define JT 128         // hidden cols per wg
#define HSTR 132       // h exchange row stride (halves)
#define HS_OFF 16384   // halves: hS overlay at byte 32768 (above 32KB scratch)
#define SMEM_BYTES (32768 + BT * HSTR * 2)   // 36992 B
#define HBUF_HALVES (BATCH * HID)            // 1 MB per buffer

typedef __attribute__((ext_vector_type(8))) short  bf16x8;
typedef __attribute__((ext_vector_type(4))) short  s16x4;
typedef __attribute__((ext_vector_type(4))) float  f32x4;
typedef __attribute__((ext_vector_type(4))) int    i32x4;
typedef __attribute__((ext_vector_type(2))) unsigned int u32x2;

__device__ __forceinline__ unsigned short f2bf(float f) {
  unsigned int u = __float_as_uint(f);
  u = (u + 0x7FFFu + ((u >> 16) & 1u)) >> 16;   // RNE
  return (unsigned short)u;
}
__device__ __forceinline__ float b2f(short h) {
  return __uint_as_float(((unsigned int)(unsigned short)h) << 16);
}

// ---- device-coherent (MALL) protocol accesses ----
__device__ __forceinline__ void store_flag(int* p, int v) {
  asm volatile("global_store_dword %0, %1, off sc0 sc1" :: "v"(p), "v"(v) : "memory");
}
__device__ __forceinline__ int load_flag(const int* p) {
  int v;
  asm volatile("global_load_dword %0, %1, off sc0 sc1\n\t"
               "s_waitcnt vmcnt(0)" : "=v"(v) : "v"(p) : "memory");
  return v;
}
__device__ __forceinline__ void store16(void* p, i32x4 v) {
  asm volatile("global_store_dwordx4 %0, %1, off sc0 sc1" :: "v"(p), "v"(v) : "memory");
}
__device__ __forceinline__ void waitcnt0() {
  asm volatile("s_waitcnt vmcnt(0)" ::: "memory");
}
// raw workgroup barrier: drains LDS ops only
__device__ __forceinline__ void barrier_lgkm() {
  asm volatile("s_waitcnt lgkmcnt(0)\n\ts_barrier" ::: "memory");
}
// 4x dwordx4 coherent loads, 64B apart (MFMA k-step stride)
__device__ __forceinline__ void issue4_64(const void* p, i32x4& a, i32x4& b, i32x4& c, i32x4& d) {
  asm volatile(
    "global_load_dwordx4 %0, %4, off sc0 sc1\n\t"
    "global_load_dwordx4 %1, %4, off offset:64 sc0 sc1\n\t"
    "global_load_dwordx4 %2, %4, off offset:128 sc0 sc1\n\t"
    "global_load_dwordx4 %3, %4, off offset:192 sc0 sc1"
    : "=&v"(a), "=&v"(b), "=&v"(c), "=&v"(d)
    : "v"(p) : "memory");
}
// 4x dwordx4 coherent loads, 16B apart (CONTIGUOUS 64 B — head staging)
__device__ __forceinline__ void issue4_16(const void* p, i32x4& a, i32x4& b, i32x4& c, i32x4& d) {
  asm volatile(
    "global_load_dwordx4 %0, %4, off sc0 sc1\n\t"
    "global_load_dwordx4 %1, %4, off offset:16 sc0 sc1\n\t"
    "global_load_dwordx4 %2, %4, off offset:32 sc0 sc1\n\t"
    "global_load_dwordx4 %3, %4, off offset:48 sc0 sc1"
    : "=&v"(a), "=&v"(b), "=&v"(c), "=&v"(d)
    : "v"(p) : "memory");
}

__device__ __forceinline__ void wr16(short* p, i32x4 v) {  // 16 B to LDS as 2x b64
  u32x2 lo, hi;
  lo.x = (unsigned)v.x; lo.y = (unsigned)v.y;
  hi.x = (unsigned)v.z; hi.y = (unsigned)v.w;
  *(u32x2*)p = lo;
  *(u32x2*)(p + 4) = hi;
}
__device__ __forceinline__ float tanh_fast(float z) {
  float e = __expf(2.f * z);
  return 1.f - 2.f / (e + 1.f);
}

#define MFMA(a, b, c) __builtin_amdgcn_mfma_f32_16x16x32_bf16((a), (b), (c), 0, 0, 0)

__global__ void __launch_bounds__(256, 1)
rnn_persistent(const float* __restrict__ x, const float* __restrict__ Whx,
               const float* __restrict__ Whh, const float* __restrict__ bh,
               const float* __restrict__ Wph, const float* __restrict__ bp,
               float* __restrict__ out, unsigned short* hbuf, int* flags)
{
  extern __shared__ short smem[];
  float* scr = (float*)smem;            // 32KB reduction scratch (head reuses)
  short* hS  = smem + HS_OFF;           // [BT][HSTR] exchange overlay

  const int tid  = threadIdx.x;
  const int bg   = blockIdx.x & 31;     // 32 batch groups
  const int jg   = blockIdx.x >> 5;     // 8 hidden slices
  const int lane = tid & 63;
  const int wv   = tid >> 6;            // wave = k-quarter owner
  const int l15  = lane & 15;
  const int quad = lane >> 4;

  // ---- W_hh into REGISTERS: cols jg*128+ct*16+l15, k = wv*256+ks*32+quad*8 ----
  bf16x8 barr[8][8];                    // 256 VGPR
#pragma unroll
  for (int ct = 0; ct < 8; ++ct) {
#pragma unroll
    for (int ks = 0; ks < 8; ++ks) {
      const float* wp = Whh + (jg * JT + ct * 16 + l15) * HID
                            + wv * 256 + ks * 32 + quad * 8;
      float4 fA = *(const float4*)(wp);
      float4 fB = *(const float4*)(wp + 4);
      union { bf16x8 v8; s16x4 h[2]; } u;
      u.h[0].x = (short)f2bf(fA.x); u.h[0].y = (short)f2bf(fA.y);
      u.h[0].z = (short)f2bf(fA.z); u.h[0].w = (short)f2bf(fA.w);
      u.h[1].x = (short)f2bf(fB.x); u.h[1].y = (short)f2bf(fB.y);
      u.h[1].z = (short)f2bf(fB.z); u.h[1].w = (short)f2bf(fB.w);
      barr[ct][ks] = u.v8;
    }
  }

  // this lane finishes col-tiles 2wv and 2wv+1 after the k-reduction
  const int j0 = jg * JT + wv * 32 + l15;
  const int j1 = j0 + 16;
  const float whx0 = Whx[j0], whx1 = Whx[j1];
  const float bhv0 = bh[j0],  bhv1 = bh[j1];

  // exchange thread mapping: 16 rows x 16 segs x 16 B
  const int sr  = tid >> 4;               // 0..15 row
  const int seg = tid & 15;               // 0..15

  int* myflags = flags + bg * 64;         // 8 flags, one 256B line per bg

  for (int t = 0; t < SEQ; ++t) {
    const unsigned short* hin = hbuf + ((t + 1) & 1) * HBUF_HALVES;
    unsigned short*      hout = hbuf + (t & 1) * HBUF_HALVES;

    f32x4 acc0 = {0,0,0,0}, acc1 = {0,0,0,0}, acc2 = {0,0,0,0}, acc3 = {0,0,0,0};
    f32x4 acc4 = {0,0,0,0}, acc5 = {0,0,0,0}, acc6 = {0,0,0,0}, acc7 = {0,0,0,0};

    // x for this step: rows bg*16 + quad*4 + rg
    float xv[4];
    {
      const float* xp = x + (bg * BT + quad * 4) * SEQ + t;
#pragma unroll
      for (int rg = 0; rg < 4; ++rg) xv[rg] = xp[rg * SEQ];
    }

    if (t > 0) {
      // acquire (R2-verified): wait for all 8 peers of this batch-group
      if (tid < GJ) {
        while (load_flag(myflags + tid) < t) {
          asm volatile("s_sleep 1" ::: "memory");
        }
      }
      __syncthreads();   // full drain: clean vmcnt window for the burst

      // A fragments direct from global in MFMA layout:
      // row l15 (BT=16: one row-tile), k-halves = wv*256 + quad*8 + ks*32.
      const short* pA = (const short*)hin + (bg * BT + l15) * HID
                        + wv * 256 + quad * 8;
      i32x4 A0, A1, A2, A3, A4, A5, A6, A7;
      issue4_64(pA,       A0, A1, A2, A3);   // ks 0..3 (byte stride 64)
      issue4_64(pA + 128, A4, A5, A6, A7);   // ks 4..7 (pA+128 halves = +256 B)

      // TIED wait (rule #18): bind every A reg so MFMAs can't hoist above it.
      asm volatile("s_waitcnt vmcnt(0)"
                   : "+v"(A0), "+v"(A1), "+v"(A2), "+v"(A3),
                     "+v"(A4), "+v"(A5), "+v"(A6), "+v"(A7)
                   :: "memory");
      __builtin_amdgcn_sched_barrier(0);

#define KSTEP(Ar, KS) { \
      bf16x8 _a = *(const bf16x8*)&(Ar); \
      acc0 = MFMA(_a, barr[0][KS], acc0); acc1 = MFMA(_a, barr[1][KS], acc1); \
      acc2 = MFMA(_a, barr[2][KS], acc2); acc3 = MFMA(_a, barr[3][KS], acc3); \
      acc4 = MFMA(_a, barr[4][KS], acc4); acc5 = MFMA(_a, barr[5][KS], acc5); \
      acc6 = MFMA(_a, barr[6][KS], acc6); acc7 = MFMA(_a, barr[7][KS], acc7); }
      KSTEP(A0, 0) KSTEP(A1, 1) KSTEP(A2, 2) KSTEP(A3, 3)
      KSTEP(A4, 4) KSTEP(A5, 5) KSTEP(A6, 6) KSTEP(A7, 7)
#undef KSTEP
    }

    // ---- cross-wave k-reduction: scr[(ct*4 + wv)*64 + lane] (f32x4 slots) ----
    barrier_lgkm();   // prior-step scratch/hS readers done
#pragma unroll
    for (int ct = 0; ct < 8; ++ct) {
      f32x4 w = (ct == 0) ? acc0 : (ct == 1) ? acc1 : (ct == 2) ? acc2 :
                (ct == 3) ? acc3 : (ct == 4) ? acc4 : (ct == 5) ? acc5 :
                (ct == 6) ? acc6 : acc7;
      *(f32x4*)(scr + ((ct * 4 + wv) * 64 + lane) * 4) = w;
    }
    barrier_lgkm();
    {
      f32x4 f0 = {0,0,0,0}, f1 = {0,0,0,0};
#pragma unroll
      for (int w = 0; w < 4; ++w) {
        f0 += *(const f32x4*)(scr + (((2 * wv)     * 4 + w) * 64 + lane) * 4);
        f1 += *(const f32x4*)(scr + (((2 * wv + 1) * 4 + w) * 64 + lane) * 4);
      }
      // h = tanh(acc + x*whx + bh) -> hS (wave wv owns col-tiles 2wv, 2wv+1)
#pragma unroll
      for (int rg = 0; rg < 4; ++rg) {
        float z0 = f0[rg] + xv[rg] * whx0 + bhv0;
        hS[(quad * 4 + rg) * HSTR + wv * 32 + l15] = (short)f2bf(tanh_fast(z0));
        float z1 = f1[rg] + xv[rg] * whx1 + bhv1;
        hS[(quad * 4 + rg) * HSTR + wv * 32 + 16 + l15] = (short)f2bf(tanh_fast(z1));
      }
    }
    barrier_lgkm();   // hS complete
    {
      const short* hsrc = hS + sr * HSTR + seg * 8;
      u32x2 lo = *(const u32x2*)(hsrc);
      u32x2 hi = *(const u32x2*)(hsrc + 4);
      i32x4 sv; sv.x = (int)lo.x; sv.y = (int)lo.y; sv.z = (int)hi.x; sv.w = (int)hi.y;
      unsigned short* dst = hout + (bg * BT + sr) * HID + jg * JT + seg * 8;
      store16(dst, sv);
    }
    waitcnt0();          // this thread's coalesced store retired at MALL
    barrier_lgkm();      // all threads retired before the flag release
    if (tid == 0) store_flag(myflags + jg, t + 1);
  }

  // ---- output head: out[b, jg*16+cc] = h_last . W_ph[c] + b_p ----
  if (tid < GJ) {
    while (load_flag(myflags + tid) < SEQ) {
      asm volatile("s_sleep 1" ::: "memory");
    }
  }
  __syncthreads();

  // stage h_last (16 x 1024 bf16 = 32KB) into smem: thread (sr, seg) owns the
  // CONTIGUOUS 128 B at row sr, bytes seg*128..+128 (fix: 16B-stride loads).
  const unsigned short* hlast = hbuf + ((SEQ - 1) & 1) * HBUF_HALVES;
  {
    const char* lbase = (const char*)(hlast + (bg * BT + sr) * HID) + seg * 128;
    i32x4 p0, p1, p2, p3, p4, p5, p6, p7;
    issue4_16(lbase,      p0, p1, p2, p3);   // bytes 0,16,32,48
    issue4_16(lbase + 64, p4, p5, p6, p7);   // bytes 64,80,96,112
    waitcnt0();
    short* sdst = smem + sr * 1028 + seg * 64;   // [16][1028] halves
    wr16(sdst,      p0); wr16(sdst + 8,  p1); wr16(sdst + 16, p2); wr16(sdst + 24, p3);
    wr16(sdst + 32, p4); wr16(sdst + 40, p5); wr16(sdst + 48, p6); wr16(sdst + 56, p7);
  }
  __syncthreads();
  {
    const int hr = tid >> 4;            // 0..15 batch row
    const int cc = tid & 15;            // 0..15 class col within slice
    const int cg = jg * 16 + cc;
    const float* wp = Wph + cg * HID;
    const short* hs = smem + hr * 1028;
    float acc = 0.f;
#pragma unroll 8
    for (int k4 = 0; k4 < 256; ++k4) {
      float4 w  = *(const float4*)(wp + k4 * 4);
      s16x4 hv  = *(const s16x4*)(hs + k4 * 4);
      acc += b2f(hv.x) * w.x + b2f(hv.y) * w.y + b2f(hv.z) * w.z + b2f(hv.w) * w.w;
    }
    out[(bg * BT + hr) * CLS + cg] = acc + bp[cg];
  }
}

extern "C" void kernel_launch(void* const* d_in, const int* in_sizes, int n_in,
                              void* d_out, int out_size, void* d_ws, size_t ws_size,
                              hipStream_t stream) {
  const float* x   = (const float*)d_in[0];
  const float* Whx = (const float*)d_in[1];
  const float* Whh = (const float*)d_in[2];
  const float* bh  = (const float*)d_in[3];
  const float* Wph = (const float*)d_in[4];
  const float* bp  = (const float*)d_in[5];
  float* out = (float*)d_out;

  unsigned short* hbuf = (unsigned short*)d_ws;
  int* flags = (int*)((char*)d_ws + (size_t)2 * HBUF_HALVES * 2);

  // Zero flags each launch (stream-ordered, capture-safe): closes the
  // cross-launch race where stale flags (=SEQ) would let consumers run ahead.
  hipMemsetAsync(flags, 0, GB * 64 * sizeof(int), stream);

  hipFuncSetAttribute(reinterpret_cast<const void*>(rnn_persistent),
                      hipFuncAttributeMaxDynamicSharedMemorySize, SMEM_BYTES);

  rnn_persistent<<<dim3(GB * GJ), dim3(256), SMEM_BYTES, stream>>>(
      x, Whx, Whh, bh, Wph, bp, out, hbuf, flags);
}